// Round 8
// baseline (436.521 us; speedup 1.0000x reference)
//
#include <hip/hip_runtime.h>
#include <hip/hip_bf16.h>
#include <string.h>

// PerformerAttention: out = (relu(xWq^T+bq) @ [relu(xWk^T+bk)^T @ (xWv^T+bv)]_per-head) Wo^T + bo
// B=4 S=8192 E=768 H=12 Dh=64.
// Round 8: gemm_bt3 — BM=256 BN=128 BK=64, 4 waves, wave tile 128x64 (43.7 FLOP/LDS-byte),
// single-buffer LDS 48 KB (3 blocks/CU, grid 768 = exactly 3/CU), stage-under-MFMA
// pipeline using only __syncthreads (frags to regs -> barrier -> restage same buf ->
// MFMA covers load latency -> barrier). Verified XOR swizzle (0 conflicts) kept.
//
// Workspace layout (bytes):
//   0        : Wq_b  (768*768*2 = 1179648)
//   1179648  : Wk_b
//   2359296  : Wv_b
//   3538944  : Wo_b
//   4718592  : Qb   [32768,768] bf16 relu'd   (50331648)
//   55050240 : Kb   [32768,768] bf16 relu'd   (later reused as QKVb)
//   105381888: Vb   [32768,768] bf16
//   155713536: P    partial KVt [48*16][64e*64d] f32 (12582912)
//   168296448: KVt  [48][64e*64d] bf16 (393216)

#define H_  12
#define DH  64
#define E_  768
#define S_  8192
#define B_  4

typedef unsigned short u16;
typedef __attribute__((ext_vector_type(4))) float f32x4;
typedef __attribute__((ext_vector_type(4))) u16   u16x4;
typedef __attribute__((ext_vector_type(8))) u16   u16x8;
typedef __attribute__((ext_vector_type(8))) short s16x8;

static __device__ __forceinline__ u16 f2bf(float f) {
    __hip_bfloat16 h = __float2bfloat16(f);   // RNE via v_cvt hardware
    u16 r; __builtin_memcpy(&r, &h, 2); return r;
}
static __device__ __forceinline__ float bf2f(u16 u) {
    unsigned int i = ((unsigned int)u) << 16;
    float f; __builtin_memcpy(&f, &i, 4); return f;
}

// async global->LDS, 16 B per lane; LDS dest is wave-uniform base + lane*16 (HW scatter).
static __device__ __forceinline__ void gload16(const void* g, void* lds) {
    __builtin_amdgcn_global_load_lds(
        (const __attribute__((address_space(1))) unsigned int*)(uintptr_t)g,
        (__attribute__((address_space(3))) unsigned int*)(uintptr_t)lds,
        16, 0, 0);
}

// ---------------- weight f32 -> bf16 (tiny) ----------------
__global__ __launch_bounds__(256) void wconv(const float* __restrict__ in,
                                             u16* __restrict__ out, int n) {
    int i = (blockIdx.x * 256 + threadIdx.x) * 4;
    if (i + 3 < n) {
        f32x4 v = *(const f32x4*)&in[i];
        u16x4 o;
        o[0] = f2bf(v[0]); o[1] = f2bf(v[1]); o[2] = f2bf(v[2]); o[3] = f2bf(v[3]);
        *(u16x4*)&out[i] = o;
    }
}

// ---------------- input f32 -> bf16, 8 elems/thread ----------------
__global__ __launch_bounds__(256) void xconv(const float* __restrict__ in,
                                             u16* __restrict__ out) {
    long i = ((long)blockIdx.x * 256 + threadIdx.x) * 8;
    f32x4 a = *(const f32x4*)&in[i];
    f32x4 b = *(const f32x4*)&in[i + 4];
    u16x8 o;
    o[0] = f2bf(a[0]); o[1] = f2bf(a[1]); o[2] = f2bf(a[2]); o[3] = f2bf(a[3]);
    o[4] = f2bf(b[0]); o[5] = f2bf(b[1]); o[6] = f2bf(b[2]); o[7] = f2bf(b[3]);
    *(u16x8*)&out[i] = o;
}

// ---------------- bf16 MFMA GEMM, NT: BM=256 BN=128 BK=64, wave tile 128x64 ----------------
// 256 threads = 4 waves (2x2): wr=(wave>>1)*128, wc=(wave&1)*64. acc[8][4] f32x4.
// LDS: As[256][64] (32 KB) + Bs[128][64] (16 KB), single buffer, row = 128 B.
// Swizzle (verified round 7, 0 conflicts): phys colbyte = logical ^ ((row&7)<<4).
// Writes: gload_lds linear dest, global source pre-unswizzled. Reads: swizzled addr.
// K-loop: read frags -> barrier (lgkm only; vmcnt already 0) -> restage same buffer
// (WAR safe) -> sched_barrier -> MFMA (hides load latency) -> barrier (drains loads).
template<int RELU, int OUT_F32>
__global__ __launch_bounds__(256) void gemm_bt3(const u16*  __restrict__ A,
                                                const u16*  __restrict__ Bw,
                                                const float* __restrict__ bias,
                                                void* __restrict__ Cp, int K) {
    __shared__ u16 As[256 * 64];   // 32 KB
    __shared__ u16 Bs[128 * 64];   // 16 KB
    const int  t    = threadIdx.x;
    const int  lane = t & 63;
    const int  wave = t >> 6;
    const long m0   = (long)blockIdx.x * 256;
    const long n0   = (long)blockIdx.y * 128;
    const int  wr   = (wave >> 1) * 128;
    const int  wc   = (wave & 1) * 64;
    const int  N    = gridDim.y * 128;

    // staging: A = 32 chunks of 1 KB (8/wave), B = 16 chunks (4/wave).
    // chunk phys offset o = chunk*1024 + lane*16; logical lo = o ^ (((o>>7)&7)<<4).
    const u16* srcA[8]; int dstA[8];
    #pragma unroll
    for (int c = 0; c < 8; ++c) {
        int ca  = wave * 8 + c;
        int o   = ca * 1024 + lane * 16;
        int lo  = o ^ (((o >> 7) & 7) << 4);
        int row = lo >> 7, colb = lo & 127;
        dstA[c] = ca * 1024;
        srcA[c] = A + (m0 + row) * (long)K + (colb >> 1);
    }
    const u16* srcB[4]; int dstB[4];
    #pragma unroll
    for (int c = 0; c < 4; ++c) {
        int cb  = wave * 4 + c;
        int o   = cb * 1024 + lane * 16;
        int lo  = o ^ (((o >> 7) & 7) << 4);
        int row = lo >> 7, colb = lo & 127;
        dstB[c] = cb * 1024;
        srcB[c] = Bw + (n0 + row) * (long)K + (colb >> 1);
    }

    // swizzled read offsets (same as round 7, verified)
    const int rb15  = lane & 15;
    const int rx    = (lane & 7) << 4;
    const int ccb   = (lane >> 4) * 16;
    const int koff0 = ccb ^ rx;
    const int koff1 = (64 + ccb) ^ rx;

    f32x4 acc[8][4] = {};

    // prologue: stage K-tile 0
    {
        char* la = (char*)As;
        char* lb = (char*)Bs;
        #pragma unroll
        for (int c = 0; c < 8; ++c) gload16(srcA[c], la + dstA[c]);
        #pragma unroll
        for (int c = 0; c < 4; ++c) gload16(srcB[c], lb + dstB[c]);
    }
    __syncthreads();

    const int nt = K >> 6;
    for (int tile = 0; tile < nt; ++tile) {
        // ---- read ALL frags of this tile into registers ----
        const char* as = (const char*)As;
        const char* bs = (const char*)Bs;
        s16x8 af[8][2], bf[4][2];
        #pragma unroll
        for (int mi = 0; mi < 8; ++mi) {
            const int rb = (wr + mi * 16 + rb15) * 128;
            af[mi][0] = *(const s16x8*)(as + rb + koff0);
            af[mi][1] = *(const s16x8*)(as + rb + koff1);
        }
        #pragma unroll
        for (int ni = 0; ni < 4; ++ni) {
            const int rb = (wc + ni * 16 + rb15) * 128;
            bf[ni][0] = *(const s16x8*)(bs + rb + koff0);
            bf[ni][1] = *(const s16x8*)(bs + rb + koff1);
        }
        __syncthreads();   // lgkm drain only (vmcnt already 0): LDS now reusable

        // ---- restage same buffer with next K-tile; latency hidden under MFMA ----
        if (tile + 1 < nt) {
            const int k0 = (tile + 1) << 6;
            char* la = (char*)As;
            char* lb = (char*)Bs;
            #pragma unroll
            for (int c = 0; c < 8; ++c) gload16(srcA[c] + k0, la + dstA[c]);
            #pragma unroll
            for (int c = 0; c < 4; ++c) gload16(srcB[c] + k0, lb + dstB[c]);
        }
        __builtin_amdgcn_sched_barrier(0);   // keep MFMA below the stage issues

        __builtin_amdgcn_s_setprio(1);
        #pragma unroll
        for (int kk = 0; kk < 2; ++kk)
            #pragma unroll
            for (int mi = 0; mi < 8; ++mi)
                #pragma unroll
                for (int ni = 0; ni < 4; ++ni)
                    acc[mi][ni] = __builtin_amdgcn_mfma_f32_16x16x32_bf16(
                        af[mi][kk], bf[ni][kk], acc[mi][ni], 0, 0, 0);
        __builtin_amdgcn_s_setprio(0);

        __syncthreads();   // drains this iter's stage (vmcnt 0): next tile ready
    }

    // ---- epilogue: C/D layout col = lane&15, row = (lane>>4)*4 + r ----
    const int cc = lane & 15;
    const int cr = (lane >> 4) * 4;
    float bv[4];
    #pragma unroll
    for (int ni = 0; ni < 4; ++ni) bv[ni] = bias[n0 + wc + ni * 16 + cc];
    #pragma unroll
    for (int mi = 0; mi < 8; ++mi) {
        #pragma unroll
        for (int r = 0; r < 4; ++r) {
            long gm = m0 + wr + mi * 16 + cr + r;
            #pragma unroll
            for (int ni = 0; ni < 4; ++ni) {
                long gn = n0 + wc + ni * 16 + cc;
                float v = acc[mi][ni][r] + bv[ni];
                if (RELU) v = fmaxf(v, 0.0f);
                if (OUT_F32) ((float*)Cp)[gm * N + gn] = v;
                else         ((u16*)Cp)[gm * N + gn]   = f2bf(v);
            }
        }
    }
}

// ---------------- KV partial v2: P[bhc][e][d] = sum_{l in chunk} V[l,e]*K[l,d] ----------------
__global__ __launch_bounds__(256) void kv_partial2(const u16* __restrict__ Kb,
                                                   const u16* __restrict__ Vb,
                                                   float* __restrict__ P) {
    __shared__ float sbuf[8192];   // per-wave: Kf[16][64] f32 + Vf[16][64] f32 (8 KB)
    const int bh = blockIdx.x, ch = blockIdx.y;
    const int b = bh / H_, h = bh - b * H_;
    const int t = threadIdx.x, lane = t & 63, wave = t >> 6;
    float* Kf = sbuf + wave * 2048;
    float* Vf = Kf + 1024;
    const long base = ((long)b * S_) * E_ + h * DH;
    const int eB = (lane >> 3) * 8;
    const int dB = (lane & 7) * 8;

    f32x4 acc[8][2] = {};

    const int l0w = ch * 512 + wave * 128;
    for (int ss = 0; ss < 8; ++ss) {
        const int l0 = l0w + ss * 16;
        #pragma unroll
        for (int half = 0; half < 2; ++half) {
            int u  = lane + half * 64;
            int lr = u >> 3, c0 = (u & 7) * 8;
            long g = base + (long)(l0 + lr) * E_ + c0;
            u16x8 kk = *(const u16x8*)&Kb[g];
            u16x8 vv = *(const u16x8*)&Vb[g];
            f32x4 k0, k1, v0, v1;
            #pragma unroll
            for (int j = 0; j < 4; ++j) {
                k0[j] = bf2f(kk[j]); k1[j] = bf2f(kk[j + 4]);
                v0[j] = bf2f(vv[j]); v1[j] = bf2f(vv[j + 4]);
            }
            *(f32x4*)&Kf[lr * 64 + c0]     = k0;
            *(f32x4*)&Kf[lr * 64 + c0 + 4] = k1;
            *(f32x4*)&Vf[lr * 64 + c0]     = v0;
            *(f32x4*)&Vf[lr * 64 + c0 + 4] = v1;
        }
        #pragma unroll
        for (int l = 0; l < 16; ++l) {
            f32x4 e0 = *(const f32x4*)&Vf[l * 64 + eB];
            f32x4 e1 = *(const f32x4*)&Vf[l * 64 + eB + 4];
            f32x4 d0 = *(const f32x4*)&Kf[l * 64 + dB];
            f32x4 d1 = *(const f32x4*)&Kf[l * 64 + dB + 4];
            #pragma unroll
            for (int i = 0; i < 4; ++i) {
                acc[i][0]     += e0[i] * d0;  acc[i][1]     += e0[i] * d1;
                acc[i + 4][0] += e1[i] * d0;  acc[i + 4][1] += e1[i] * d1;
            }
        }
    }

    __syncthreads();
    if (wave >= 2) {
        float* r = sbuf + (wave - 2) * 4096;
        #pragma unroll
        for (int i = 0; i < 8; ++i) {
            *(f32x4*)&r[(eB + i) * 64 + dB]     = acc[i][0];
            *(f32x4*)&r[(eB + i) * 64 + dB + 4] = acc[i][1];
        }
    }
    __syncthreads();
    if (wave < 2) {
        const float* r = sbuf + wave * 4096;
        #pragma unroll
        for (int i = 0; i < 8; ++i) {
            acc[i][0] += *(const f32x4*)&r[(eB + i) * 64 + dB];
            acc[i][1] += *(const f32x4*)&r[(eB + i) * 64 + dB + 4];
        }
    }
    __syncthreads();
    if (wave == 1) {
        #pragma unroll
        for (int i = 0; i < 8; ++i) {
            *(f32x4*)&sbuf[(eB + i) * 64 + dB]     = acc[i][0];
            *(f32x4*)&sbuf[(eB + i) * 64 + dB + 4] = acc[i][1];
        }
    }
    __syncthreads();
    if (wave == 0) {
        float* Pp = &P[((long)(bh * 16 + ch)) * 4096];
        #pragma unroll
        for (int i = 0; i < 8; ++i) {
            f32x4 s0 = acc[i][0] + *(const f32x4*)&sbuf[(eB + i) * 64 + dB];
            f32x4 s1 = acc[i][1] + *(const f32x4*)&sbuf[(eB + i) * 64 + dB + 4];
            *(f32x4*)&Pp[(eB + i) * 64 + dB]     = s0;
            *(f32x4*)&Pp[(eB + i) * 64 + dB + 4] = s1;
        }
    }
}

// ---------------- KV reduce: sum 16 chunks, write bf16 KVt[bh][e*64+d] ----------------
__global__ __launch_bounds__(256) void kv_reduce(const float* __restrict__ P,
                                                 u16* __restrict__ KVt) {
    const int bh = blockIdx.x, t = threadIdx.x;
    #pragma unroll
    for (int k = 0; k < 4; ++k) {
        int i = t * 4 + k * 1024;
        f32x4 s = {};
        for (int c = 0; c < 16; ++c) s += *(const f32x4*)&P[((long)(bh * 16 + c)) * 4096 + i];
        u16x4 o;
        #pragma unroll
        for (int j = 0; j < 4; ++j) o[j] = f2bf(s[j]);
        *(u16x4*)&KVt[(long)bh * 4096 + i] = o;
    }
}

// ---------------- QKV via MFMA: C[l][e] = sum_d Q[l][d] * KVt[e][d] ----------------
__global__ __launch_bounds__(256) void qkv_mfma(const u16* __restrict__ Qb,
                                                const u16* __restrict__ KVt,
                                                u16* __restrict__ Ob) {
    __shared__ u16 Qs[256 * 64];   // 32 KB
    __shared__ u16 Ks[64 * 64];    // 8 KB
    const int t = threadIdx.x, lane = t & 63, wave = t >> 6;
    const int h = blockIdx.y, b = blockIdx.z;
    const long r0 = (long)b * S_ + (long)blockIdx.x * 256;

    {
        char* lq = (char*)Qs;
        #pragma unroll
        for (int j = 0; j < 8; ++j) {
            int ob = (wave * 8 + j) * 1024;
            int ol = ob + lane * 16;
            int row = ol >> 7, col = (ol & 127) >> 1;
            gload16(&Qb[(r0 + row) * E_ + h * DH + col], lq + ob);
        }
        char* lk = (char*)Ks;
        #pragma unroll
        for (int j = 0; j < 2; ++j) {
            int ob = (wave * 2 + j) * 1024;
            int ol = ob + lane * 16;
            int row = ol >> 7, col = (ol & 127) >> 1;
            gload16(&KVt[((long)(b * H_ + h)) * 4096 + row * 64 + col], lk + ob);
        }
    }
    __syncthreads();

    f32x4 acc[4][4] = {};
    #pragma unroll
    for (int kk = 0; kk < 2; ++kk) {
        s16x8 af[4], bfr[4];
        #pragma unroll
        for (int mi = 0; mi < 4; ++mi)
            af[mi] = *(const s16x8*)&Qs[(wave * 64 + mi * 16 + (lane & 15)) * 64 + kk * 32 + (lane >> 4) * 8];
        #pragma unroll
        for (int ni = 0; ni < 4; ++ni)
            bfr[ni] = *(const s16x8*)&Ks[(ni * 16 + (lane & 15)) * 64 + kk * 32 + (lane >> 4) * 8];
        #pragma unroll
        for (int mi = 0; mi < 4; ++mi)
            #pragma unroll
            for (int ni = 0; ni < 4; ++ni)
                acc[mi][ni] = __builtin_amdgcn_mfma_f32_16x16x32_bf16(af[mi], bfr[ni], acc[mi][ni], 0, 0, 0);
    }

    const int cc = lane & 15, cr = (lane >> 4) * 4;
    #pragma unroll
    for (int mi = 0; mi < 4; ++mi) {
        #pragma unroll
        for (int r = 0; r < 4; ++r) {
            long gm = r0 + wave * 64 + mi * 16 + cr + r;
            #pragma unroll
            for (int ni = 0; ni < 4; ++ni)
                Ob[gm * E_ + h * DH + ni * 16 + cc] = f2bf(acc[mi][ni][r]);
        }
    }
}

extern "C" void kernel_launch(void* const* d_in, const int* in_sizes, int n_in,
                              void* d_out, int out_size, void* d_ws, size_t ws_size,
                              hipStream_t stream) {
    const float* q  = (const float*)d_in[0];
    const float* k  = (const float*)d_in[1];
    const float* v  = (const float*)d_in[2];
    const float* Wq = (const float*)d_in[3];
    const float* bq = (const float*)d_in[4];
    const float* Wk = (const float*)d_in[5];
    const float* bk = (const float*)d_in[6];
    const float* Wv = (const float*)d_in[7];
    const float* bv = (const float*)d_in[8];
    const float* Wo = (const float*)d_in[9];
    const float* bo = (const float*)d_in[10];
    float* out = (float*)d_out;

    char* ws = (char*)d_ws;
    u16*   Wq_b = (u16*)(ws);
    u16*   Wk_b = (u16*)(ws + 1179648L);
    u16*   Wv_b = (u16*)(ws + 2359296L);
    u16*   Wo_b = (u16*)(ws + 3538944L);
    u16*   Qb   = (u16*)(ws + 4718592L);
    u16*   Kb   = (u16*)(ws + 55050240L);
    u16*   Vb   = (u16*)(ws + 105381888L);
    float* P    = (float*)(ws + 155713536L);
    u16*   KVt  = (u16*)(ws + 168296448L);
    u16*   QKVb = Kb;            // Kb dead after kv_partial2 — reuse
    u16*   xb   = (u16*)d_out;   // d_out as conversion scratch; overwritten by final GEMM

    dim3 blk(256);
    wconv<<<576, blk, 0, stream>>>(Wq, Wq_b, 589824);
    wconv<<<576, blk, 0, stream>>>(Wk, Wk_b, 589824);
    wconv<<<576, blk, 0, stream>>>(Wv, Wv_b, 589824);
    wconv<<<576, blk, 0, stream>>>(Wo, Wo_b, 589824);

    dim3 g1(128, 6);  // M=32768/256, N=768/128 -> 768 blocks = 3/CU exactly
    xconv<<<12288, blk, 0, stream>>>(q, xb);
    gemm_bt3<1, 0><<<g1, blk, 0, stream>>>(xb, Wq_b, bq, Qb, 768);
    xconv<<<12288, blk, 0, stream>>>(k, xb);
    gemm_bt3<1, 0><<<g1, blk, 0, stream>>>(xb, Wk_b, bk, Kb, 768);
    xconv<<<12288, blk, 0, stream>>>(v, xb);
    gemm_bt3<0, 0><<<g1, blk, 0, stream>>>(xb, Wv_b, bv, Vb, 768);

    kv_partial2<<<dim3(48, 16), blk, 0, stream>>>(Kb, Vb, P);
    kv_reduce<<<48, blk, 0, stream>>>(P, KVt);
    qkv_mfma<<<dim3(32, 12, 4), blk, 0, stream>>>(Qb, KVt, QKVb);

    gemm_bt3<0, 1><<<g1, blk, 0, stream>>>(QKVb, Wo_b, bo, out, 768);
}

// Round 9
// 386.818 us; speedup vs baseline: 1.1285x; 1.1285x over previous
//
#include <hip/hip_runtime.h>
#include <hip/hip_bf16.h>
#include <string.h>

// PerformerAttention: out = (relu(xWq^T+bq) @ [relu(xWk^T+bk)^T @ (xWv^T+bv)]_per-head) Wo^T + bo
// B=4 S=8192 E=768 H=12 Dh=64.
// Round 9: revert GEMM scheduling to round-7 bt2 (verified 69us). New:
//  (a) gemm_f32a: cvt fused into A-staging (reg-staged A: f32 global -> cvt -> swizzled
//      ds_write; B via global_load_lds). Kills xconv (-78us).
//  (b) W2 fusion: out = Qr @ W2[b]^T with W2t[b][n][(h,d)] = sum_e KV[b,h,d,e]*Wo[n][(h,e)]
//      (tiny batched GEMM w2prep). Kills qkv_mfma (-18us).
//
// Workspace layout (bytes):
//   0        : Wq_b  (768*768*2 = 1179648)
//   1179648  : Wk_b
//   2359296  : Wv_b
//   3538944  : Wo_b
//   4718592  : Qb   [32768,768] bf16 relu'd   (50331648)
//   55050240 : Kb   [32768,768] bf16 relu'd   (reused as W2t [4][768][768] bf16 after death)
//   105381888: Vb   [32768,768] bf16
//   155713536: P    partial KVt [48*16][64e*64d] f32 (12582912)
//   168296448: KVde [48][64d*64e] bf16 (393216)   end = 168689664

#define H_  12
#define DH  64
#define E_  768
#define S_  8192
#define B_  4

typedef unsigned short u16;
typedef __attribute__((ext_vector_type(4))) float f32x4;
typedef __attribute__((ext_vector_type(4))) u16   u16x4;
typedef __attribute__((ext_vector_type(8))) u16   u16x8;
typedef __attribute__((ext_vector_type(8))) short s16x8;

static __device__ __forceinline__ u16 f2bf(float f) {
    __hip_bfloat16 h = __float2bfloat16(f);   // RNE via v_cvt hardware
    u16 r; __builtin_memcpy(&r, &h, 2); return r;
}
static __device__ __forceinline__ float bf2f(u16 u) {
    unsigned int i = ((unsigned int)u) << 16;
    float f; __builtin_memcpy(&f, &i, 4); return f;
}

// async global->LDS, 16 B per lane; LDS dest is wave-uniform base + lane*16 (HW scatter).
static __device__ __forceinline__ void gload16(const void* g, void* lds) {
    __builtin_amdgcn_global_load_lds(
        (const __attribute__((address_space(1))) unsigned int*)(uintptr_t)g,
        (__attribute__((address_space(3))) unsigned int*)(uintptr_t)lds,
        16, 0, 0);
}

// ---------------- weight f32 -> bf16 (tiny) ----------------
__global__ __launch_bounds__(256) void wconv(const float* __restrict__ in,
                                             u16* __restrict__ out, int n) {
    int i = (blockIdx.x * 256 + threadIdx.x) * 4;
    if (i + 3 < n) {
        f32x4 v = *(const f32x4*)&in[i];
        u16x4 o;
        o[0] = f2bf(v[0]); o[1] = f2bf(v[1]); o[2] = f2bf(v[2]); o[3] = f2bf(v[3]);
        *(u16x4*)&out[i] = o;
    }
}

// ======== GEMM with fused f32->bf16 A-staging (projections) =================
// BM=BN=128, BK=64, dbuf, 4 waves (2x2), wave tile 64x64, acc[4][4].
// A: reg-staged (f32 global -> cvt -> swizzled ds_write_b128). B: gload_lds with
// pre-unswizzled source. Swizzle (verified r7, 0 conflicts): phys = lo ^ ((row&7)<<4).
// Iter: [issue A f32 loads (t+1)] [issue B gloads (t+1)->buf^1] [frag ds_reads buf]
//       [MFMA] [cvt+ds_write A (t+1)->buf^1] [__syncthreads].
template<int RELU>
__global__ __launch_bounds__(256) void gemm_f32a(const float* __restrict__ A,
                                                 const u16*  __restrict__ Bw,
                                                 const float* __restrict__ bias,
                                                 u16* __restrict__ Cp, int K) {
    __shared__ u16 As[2][128 * 64];
    __shared__ u16 Bs[2][128 * 64];
    const int  t    = threadIdx.x;
    const int  lane = t & 63;
    const int  wave = t >> 6;
    const long m0   = (long)blockIdx.x * 128;
    const long n0   = (long)blockIdx.y * 128;
    const int  wr   = (wave >> 1) * 64;
    const int  wc   = (wave & 1) * 64;
    const int  N    = gridDim.y * 128;

    // B staging: 16 chunks of 1 KB, 4/wave; gload_lds linear dest, pre-unswizzled src.
    const u16* srcB[4]; int dstB[4];
    #pragma unroll
    for (int c = 0; c < 4; ++c) {
        int cb  = wave * 4 + c;
        int o   = cb * 1024 + lane * 16;
        int lo  = o ^ (((o >> 7) & 7) << 4);
        int row = lo >> 7, colb = lo & 127;
        dstB[c] = cb * 1024;
        srcB[c] = Bw + (n0 + row) * (long)K + (colb >> 1);
    }
    // A staging: thread handles 4 groups of 8 elems; group g = j*256+t,
    // row = g>>3, col = (g&7)*8; write byte = (row*128 + col*2) ^ ((row&7)<<4).
    const float* asrc[4]; int adst[4];
    #pragma unroll
    for (int j = 0; j < 4; ++j) {
        int g   = j * 256 + t;
        int row = g >> 3, col = (g & 7) * 8;
        int lo  = row * 128 + col * 2;
        adst[j] = lo ^ ((row & 7) << 4);
        asrc[j] = A + (m0 + row) * (long)K + col;
    }

    // swizzled read offsets (verified r7)
    const int rb15  = lane & 15;
    const int rx    = (lane & 7) << 4;
    const int ccb   = (lane >> 4) * 16;
    const int koff0 = ccb ^ rx;
    const int koff1 = (64 + ccb) ^ rx;

    f32x4 acc[4][4] = {};

    // prologue: stage K-tile 0 into buf 0
    {
        f32x4 av0[4], av1[4];
        #pragma unroll
        for (int j = 0; j < 4; ++j) {
            av0[j] = *(const f32x4*)(asrc[j]);
            av1[j] = *(const f32x4*)(asrc[j] + 4);
        }
        #pragma unroll
        for (int c = 0; c < 4; ++c) gload16(srcB[c], (char*)&Bs[0][0] + dstB[c]);
        #pragma unroll
        for (int j = 0; j < 4; ++j) {
            u16x8 o8;
            #pragma unroll
            for (int x = 0; x < 4; ++x) { o8[x] = f2bf(av0[j][x]); o8[x + 4] = f2bf(av1[j][x]); }
            *(u16x8*)((char*)&As[0][0] + adst[j]) = o8;
        }
    }
    __syncthreads();

    const int nk = K >> 6;
    for (int kt = 0; kt < nk; ++kt) {
        const int nxt = (kt + 1) & 1;
        f32x4 av0[4], av1[4];
        if (kt + 1 < nk) {
            const int k0 = (kt + 1) << 6;
            // A loads first (older in vmcnt queue -> cvt waits only on these)
            #pragma unroll
            for (int j = 0; j < 4; ++j) {
                av0[j] = *(const f32x4*)(asrc[j] + k0);
                av1[j] = *(const f32x4*)(asrc[j] + k0 + 4);
            }
            #pragma unroll
            for (int c = 0; c < 4; ++c) gload16(srcB[c] + k0, (char*)&Bs[nxt][0] + dstB[c]);
        }

        const char* as = (const char*)&As[kt & 1][0];
        const char* bs = (const char*)&Bs[kt & 1][0];
        s16x8 af[4][2], bf[4][2];
        #pragma unroll
        for (int mi = 0; mi < 4; ++mi) {
            const int rb = (wr + mi * 16 + rb15) * 128;
            af[mi][0] = *(const s16x8*)(as + rb + koff0);
            af[mi][1] = *(const s16x8*)(as + rb + koff1);
        }
        #pragma unroll
        for (int ni = 0; ni < 4; ++ni) {
            const int rb = (wc + ni * 16 + rb15) * 128;
            bf[ni][0] = *(const s16x8*)(bs + rb + koff0);
            bf[ni][1] = *(const s16x8*)(bs + rb + koff1);
        }

        __builtin_amdgcn_s_setprio(1);
        #pragma unroll
        for (int kk = 0; kk < 2; ++kk)
            #pragma unroll
            for (int mi = 0; mi < 4; ++mi)
                #pragma unroll
                for (int ni = 0; ni < 4; ++ni)
                    acc[mi][ni] = __builtin_amdgcn_mfma_f32_16x16x32_bf16(
                        af[mi][kk], bf[ni][kk], acc[mi][ni], 0, 0, 0);
        __builtin_amdgcn_s_setprio(0);

        if (kt + 1 < nk) {
            #pragma unroll
            for (int j = 0; j < 4; ++j) {
                u16x8 o8;
                #pragma unroll
                for (int x = 0; x < 4; ++x) { o8[x] = f2bf(av0[j][x]); o8[x + 4] = f2bf(av1[j][x]); }
                *(u16x8*)((char*)&As[nxt][0] + adst[j]) = o8;
            }
        }
        __syncthreads();   // drains B gloads (vmcnt) + A ds_writes (lgkm)
    }

    // epilogue: C/D layout col = lane&15, row = (lane>>4)*4 + r
    const int cc = lane & 15;
    const int cr = (lane >> 4) * 4;
    float bv[4];
    #pragma unroll
    for (int ni = 0; ni < 4; ++ni) bv[ni] = bias[n0 + wc + ni * 16 + cc];
    #pragma unroll
    for (int mi = 0; mi < 4; ++mi) {
        #pragma unroll
        for (int r = 0; r < 4; ++r) {
            long gm = m0 + wr + mi * 16 + cr + r;
            #pragma unroll
            for (int ni = 0; ni < 4; ++ni) {
                long gn = n0 + wc + ni * 16 + cc;
                float v = acc[mi][ni][r] + bv[ni];
                if (RELU) v = fmaxf(v, 0.0f);
                Cp[gm * N + gn] = f2bf(v);
            }
        }
    }
}

// ======== bf16 GEMM (round-7 bt2, verified) — final out GEMM with per-b W2 ====
template<int PERB>
__global__ __launch_bounds__(256) void gemm_bt2(const u16*  __restrict__ A,
                                                const u16*  __restrict__ Bw0,
                                                const float* __restrict__ bias,
                                                float* __restrict__ Cp, int K) {
    __shared__ u16 As[2][128 * 64];
    __shared__ u16 Bs[2][128 * 64];
    const int  t    = threadIdx.x;
    const int  lane = t & 63;
    const int  wave = t >> 6;
    const long m0   = (long)blockIdx.x * 128;
    const long n0   = (long)blockIdx.y * 128;
    const int  wr   = (wave >> 1) * 64;
    const int  wc   = (wave & 1) * 64;
    const int  N    = gridDim.y * 128;
    const u16* Bw   = PERB ? (Bw0 + (m0 >> 13) * 589824L) : Bw0;

    const u16* srcA[4]; const u16* srcB[4]; int dstc[4];
    #pragma unroll
    for (int c = 0; c < 4; ++c) {
        int o   = (wave * 4 + c) * 1024 + lane * 16;
        int lo  = o ^ (((o >> 7) & 7) << 4);
        int row = lo >> 7, colb = lo & 127;
        dstc[c] = (wave * 4 + c) * 1024;
        srcA[c] = A  + (m0 + row) * (long)K + (colb >> 1);
        srcB[c] = Bw + (n0 + row) * (long)K + (colb >> 1);
    }

    const int rb15  = lane & 15;
    const int rx    = (lane & 7) << 4;
    const int ccb   = (lane >> 4) * 16;
    const int koff0 = ccb ^ rx;
    const int koff1 = (64 + ccb) ^ rx;

    f32x4 acc[4][4] = {};

    {
        char* la = (char*)&As[0][0];
        char* lb = (char*)&Bs[0][0];
        #pragma unroll
        for (int c = 0; c < 4; ++c) gload16(srcA[c], la + dstc[c]);
        #pragma unroll
        for (int c = 0; c < 4; ++c) gload16(srcB[c], lb + dstc[c]);
    }
    __syncthreads();

    const int nk = K >> 6;
    for (int kt = 0; kt < nk; ++kt) {
        if (kt + 1 < nk) {
            const int k0 = (kt + 1) << 6;
            char* la = (char*)&As[(kt + 1) & 1][0];
            char* lb = (char*)&Bs[(kt + 1) & 1][0];
            #pragma unroll
            for (int c = 0; c < 4; ++c) gload16(srcA[c] + k0, la + dstc[c]);
            #pragma unroll
            for (int c = 0; c < 4; ++c) gload16(srcB[c] + k0, lb + dstc[c]);
        }

        const char* as = (const char*)&As[kt & 1][0];
        const char* bs = (const char*)&Bs[kt & 1][0];
        s16x8 af[4][2], bf[4][2];
        #pragma unroll
        for (int mi = 0; mi < 4; ++mi) {
            const int rb = (wr + mi * 16 + rb15) * 128;
            af[mi][0] = *(const s16x8*)(as + rb + koff0);
            af[mi][1] = *(const s16x8*)(as + rb + koff1);
        }
        #pragma unroll
        for (int ni = 0; ni < 4; ++ni) {
            const int rb = (wc + ni * 16 + rb15) * 128;
            bf[ni][0] = *(const s16x8*)(bs + rb + koff0);
            bf[ni][1] = *(const s16x8*)(bs + rb + koff1);
        }

        __builtin_amdgcn_s_setprio(1);
        #pragma unroll
        for (int kk = 0; kk < 2; ++kk)
            #pragma unroll
            for (int mi = 0; mi < 4; ++mi)
                #pragma unroll
                for (int ni = 0; ni < 4; ++ni)
                    acc[mi][ni] = __builtin_amdgcn_mfma_f32_16x16x32_bf16(
                        af[mi][kk], bf[ni][kk], acc[mi][ni], 0, 0, 0);
        __builtin_amdgcn_s_setprio(0);

        __syncthreads();
    }

    const int cc = lane & 15;
    const int cr = (lane >> 4) * 4;
    float bv[4];
    #pragma unroll
    for (int ni = 0; ni < 4; ++ni) bv[ni] = bias[n0 + wc + ni * 16 + cc];
    #pragma unroll
    for (int mi = 0; mi < 4; ++mi) {
        #pragma unroll
        for (int r = 0; r < 4; ++r) {
            long gm = m0 + wr + mi * 16 + cr + r;
            #pragma unroll
            for (int ni = 0; ni < 4; ++ni) {
                long gn = n0 + wc + ni * 16 + cc;
                Cp[gm * N + gn] = acc[mi][ni][r] + bv[ni];
            }
        }
    }
}

// ---------------- KV partial v2 (unchanged): P[bhc][e][d] = sum_l V[l,e]*K[l,d] -------
__global__ __launch_bounds__(256) void kv_partial2(const u16* __restrict__ Kb,
                                                   const u16* __restrict__ Vb,
                                                   float* __restrict__ P) {
    __shared__ float sbuf[8192];
    const int bh = blockIdx.x, ch = blockIdx.y;
    const int b = bh / H_, h = bh - b * H_;
    const int t = threadIdx.x, lane = t & 63, wave = t >> 6;
    float* Kf = sbuf + wave * 2048;
    float* Vf = Kf + 1024;
    const long base = ((long)b * S_) * E_ + h * DH;
    const int eB = (lane >> 3) * 8;
    const int dB = (lane & 7) * 8;

    f32x4 acc[8][2] = {};

    const int l0w = ch * 512 + wave * 128;
    for (int ss = 0; ss < 8; ++ss) {
        const int l0 = l0w + ss * 16;
        #pragma unroll
        for (int half = 0; half < 2; ++half) {
            int u  = lane + half * 64;
            int lr = u >> 3, c0 = (u & 7) * 8;
            long g = base + (long)(l0 + lr) * E_ + c0;
            u16x8 kk = *(const u16x8*)&Kb[g];
            u16x8 vv = *(const u16x8*)&Vb[g];
            f32x4 k0, k1, v0, v1;
            #pragma unroll
            for (int j = 0; j < 4; ++j) {
                k0[j] = bf2f(kk[j]); k1[j] = bf2f(kk[j + 4]);
                v0[j] = bf2f(vv[j]); v1[j] = bf2f(vv[j + 4]);
            }
            *(f32x4*)&Kf[lr * 64 + c0]     = k0;
            *(f32x4*)&Kf[lr * 64 + c0 + 4] = k1;
            *(f32x4*)&Vf[lr * 64 + c0]     = v0;
            *(f32x4*)&Vf[lr * 64 + c0 + 4] = v1;
        }
        #pragma unroll
        for (int l = 0; l < 16; ++l) {
            f32x4 e0 = *(const f32x4*)&Vf[l * 64 + eB];
            f32x4 e1 = *(const f32x4*)&Vf[l * 64 + eB + 4];
            f32x4 d0 = *(const f32x4*)&Kf[l * 64 + dB];
            f32x4 d1 = *(const f32x4*)&Kf[l * 64 + dB + 4];
            #pragma unroll
            for (int i = 0; i < 4; ++i) {
                acc[i][0]     += e0[i] * d0;  acc[i][1]     += e0[i] * d1;
                acc[i + 4][0] += e1[i] * d0;  acc[i + 4][1] += e1[i] * d1;
            }
        }
    }

    __syncthreads();
    if (wave >= 2) {
        float* r = sbuf + (wave - 2) * 4096;
        #pragma unroll
        for (int i = 0; i < 8; ++i) {
            *(f32x4*)&r[(eB + i) * 64 + dB]     = acc[i][0];
            *(f32x4*)&r[(eB + i) * 64 + dB + 4] = acc[i][1];
        }
    }
    __syncthreads();
    if (wave < 2) {
        const float* r = sbuf + wave * 4096;
        #pragma unroll
        for (int i = 0; i < 8; ++i) {
            acc[i][0] += *(const f32x4*)&r[(eB + i) * 64 + dB];
            acc[i][1] += *(const f32x4*)&r[(eB + i) * 64 + dB + 4];
        }
    }
    __syncthreads();
    if (wave == 1) {
        #pragma unroll
        for (int i = 0; i < 8; ++i) {
            *(f32x4*)&sbuf[(eB + i) * 64 + dB]     = acc[i][0];
            *(f32x4*)&sbuf[(eB + i) * 64 + dB + 4] = acc[i][1];
        }
    }
    __syncthreads();
    if (wave == 0) {
        float* Pp = &P[((long)(bh * 16 + ch)) * 4096];
        #pragma unroll
        for (int i = 0; i < 8; ++i) {
            f32x4 s0 = acc[i][0] + *(const f32x4*)&sbuf[(eB + i) * 64 + dB];
            f32x4 s1 = acc[i][1] + *(const f32x4*)&sbuf[(eB + i) * 64 + dB + 4];
            *(f32x4*)&Pp[(eB + i) * 64 + dB]     = s0;
            *(f32x4*)&Pp[(eB + i) * 64 + dB + 4] = s1;
        }
    }
}

// ---------------- KV reduce (transposing): KVde[bh][d*64+e] bf16 ----------------
__global__ __launch_bounds__(256) void kv_reduce2(const float* __restrict__ P,
                                                  u16* __restrict__ KVde) {
    const int bh = blockIdx.x, t = threadIdx.x;
    #pragma unroll
    for (int k = 0; k < 4; ++k) {
        int i = t * 4 + k * 1024;        // linear over [e][d], d fastest
        f32x4 s = {};
        for (int c = 0; c < 16; ++c) s += *(const f32x4*)&P[((long)(bh * 16 + c)) * 4096 + i];
        const int e = i >> 6, d0 = i & 63;
        #pragma unroll
        for (int j = 0; j < 4; ++j)
            KVde[(long)bh * 4096 + (d0 + j) * 64 + e] = f2bf(s[j]);
    }
}

// ---------------- w2prep: W2t[b][n][(h,d)] = sum_e Wo[n][(h,e)] * KVde[b,h][d][e] ----
// grid (3 nblk, 12 h, 4 b); 256 thr = 4 waves; wave w: rows n [w*64,+64) x 64 d. K=64.
__global__ __launch_bounds__(256) void w2prep(const u16* __restrict__ Wo_b,
                                              const u16* __restrict__ KVde,
                                              u16* __restrict__ W2t) {
    __shared__ u16 Qs[256 * 64];   // Wo rows tile [256 n][64 e]
    __shared__ u16 Ks[64 * 64];    // KVde tile [64 d][64 e]
    const int t = threadIdx.x, lane = t & 63, wave = t >> 6;
    const int h = blockIdx.y, b = blockIdx.z;
    const int n0 = blockIdx.x * 256;

    {
        char* lq = (char*)Qs;
        #pragma unroll
        for (int j = 0; j < 8; ++j) {
            int ob = (wave * 8 + j) * 1024;
            int ol = ob + lane * 16;
            int row = ol >> 7, col = (ol & 127) >> 1;
            gload16(&Wo_b[(long)(n0 + row) * E_ + h * DH + col], lq + ob);
        }
        char* lk = (char*)Ks;
        #pragma unroll
        for (int j = 0; j < 2; ++j) {
            int ob = (wave * 2 + j) * 1024;
            int ol = ob + lane * 16;
            int row = ol >> 7, col = (ol & 127) >> 1;
            gload16(&KVde[((long)(b * H_ + h)) * 4096 + row * 64 + col], lk + ob);
        }
    }
    __syncthreads();

    f32x4 acc[4][4] = {};
    #pragma unroll
    for (int kk = 0; kk < 2; ++kk) {
        s16x8 af[4], bfr[4];
        #pragma unroll
        for (int mi = 0; mi < 4; ++mi)
            af[mi] = *(const s16x8*)&Qs[(wave * 64 + mi * 16 + (lane & 15)) * 64 + kk * 32 + (lane >> 4) * 8];
        #pragma unroll
        for (int ni = 0; ni < 4; ++ni)
            bfr[ni] = *(const s16x8*)&Ks[(ni * 16 + (lane & 15)) * 64 + kk * 32 + (lane >> 4) * 8];
        #pragma unroll
        for (int mi = 0; mi < 4; ++mi)
            #pragma unroll
            for (int ni = 0; ni < 4; ++ni)
                acc[mi][ni] = __builtin_amdgcn_mfma_f32_16x16x32_bf16(af[mi], bfr[ni], acc[mi][ni], 0, 0, 0);
    }

    const int cc = lane & 15, cr = (lane >> 4) * 4;
    u16* Wb = W2t + (long)b * 589824L;
    #pragma unroll
    for (int mi = 0; mi < 4; ++mi) {
        #pragma unroll
        for (int r = 0; r < 4; ++r) {
            long gm = n0 + wave * 64 + mi * 16 + cr + r;   // n row
            #pragma unroll
            for (int ni = 0; ni < 4; ++ni)
                Wb[gm * E_ + h * DH + ni * 16 + cc] = f2bf(acc[mi][ni][r]);
        }
    }
}

extern "C" void kernel_launch(void* const* d_in, const int* in_sizes, int n_in,
                              void* d_out, int out_size, void* d_ws, size_t ws_size,
                              hipStream_t stream) {
    const float* q  = (const float*)d_in[0];
    const float* k  = (const float*)d_in[1];
    const float* v  = (const float*)d_in[2];
    const float* Wq = (const float*)d_in[3];
    const float* bq = (const float*)d_in[4];
    const float* Wk = (const float*)d_in[5];
    const float* bk = (const float*)d_in[6];
    const float* Wv = (const float*)d_in[7];
    const float* bv = (const float*)d_in[8];
    const float* Wo = (const float*)d_in[9];
    const float* bo = (const float*)d_in[10];
    float* out = (float*)d_out;

    char* ws = (char*)d_ws;
    u16*   Wq_b = (u16*)(ws);
    u16*   Wk_b = (u16*)(ws + 1179648L);
    u16*   Wv_b = (u16*)(ws + 2359296L);
    u16*   Wo_b = (u16*)(ws + 3538944L);
    u16*   Qb   = (u16*)(ws + 4718592L);
    u16*   Kb   = (u16*)(ws + 55050240L);
    u16*   Vb   = (u16*)(ws + 105381888L);
    float* P    = (float*)(ws + 155713536L);
    u16*   KVde = (u16*)(ws + 168296448L);
    u16*   W2t  = Kb;   // Kb dead after kv_partial2 — reuse (4.7 MB needed)

    dim3 blk(256);
    wconv<<<576, blk, 0, stream>>>(Wq, Wq_b, 589824);
    wconv<<<576, blk, 0, stream>>>(Wk, Wk_b, 589824);
    wconv<<<576, blk, 0, stream>>>(Wv, Wv_b, 589824);
    wconv<<<576, blk, 0, stream>>>(Wo, Wo_b, 589824);

    dim3 g1(256, 6);  // M=32768/128, N=768/128
    gemm_f32a<1><<<g1, blk, 0, stream>>>(q, Wq_b, bq, Qb, 768);
    gemm_f32a<1><<<g1, blk, 0, stream>>>(k, Wk_b, bk, Kb, 768);
    gemm_f32a<0><<<g1, blk, 0, stream>>>(v, Wv_b, bv, Vb, 768);

    kv_partial2<<<dim3(48, 16), blk, 0, stream>>>(Kb, Vb, P);
    kv_reduce2<<<48, blk, 0, stream>>>(P, KVde);
    w2prep<<<dim3(3, 12, 4), blk, 0, stream>>>(Wo_b, KVde, W2t);

    gemm_bt2<1><<<g1, blk, 0, stream>>>(Qb, W2t, bo, out, 768);
}